// Round 1
// baseline (1130.066 us; speedup 1.0000x reference)
//
#include <hip/hip_runtime.h>

// Problem constants (from reference)
constexpr int B_ = 8;
constexpr int N_ = 16384;
constexpr int NG = 512;     // NUM_GROUPS
constexpr int GS = 32;      // GROUP_SIZE
constexpr int KORIG = 160;  // K_ORIGINAL = 5*GROUP_SIZE
// radius^2: reference compares d2 < float32(0.2*0.2 in f64) == 0.04f (0x3D23D70A)
#define R2 0.04f
#define RADIUS 0.2f

__device__ __forceinline__ unsigned f32_ord(float f) {
  unsigned u = __float_as_uint(f);
  return (u & 0x80000000u) ? ~u : (u | 0x80000000u);
}

// ---------------- Kernel 1: farthest point sampling ----------------
// One block per batch. 1024 threads, 16 points/thread in registers.
// Exact semantics: mindist=where(valid,min(mindist,d),-inf); argmax first-index tie-break.
__global__ __launch_bounds__(1024) void fps_kernel(const float4* __restrict__ p4,
                                                   const int* __restrict__ lengths,
                                                   float* __restrict__ centers) {
#pragma clang fp contract(off)
  const int b = blockIdx.x;
  const int t = threadIdx.x;
  const int len = lengths[b];
  const float4* bp = p4 + (size_t)b * N_;

  __shared__ float s_cx, s_cy, s_cz;
  __shared__ unsigned long long s_wkey[16];
  __shared__ int s_sel[NG];

  float x[16], y[16], z[16], mind[16];
#pragma unroll
  for (int j = 0; j < 16; ++j) {
    int i = t + j * 1024;
    float4 p = bp[i];
    x[j] = p.x; y[j] = p.y; z[j] = p.z;
    mind[j] = (i < len) ? __builtin_inff() : -__builtin_inff();
  }
  if (t == 0) {
    s_sel[0] = 0;  // reference scan starts at cur=0
    float4 c0 = bp[0];
    s_cx = c0.x; s_cy = c0.y; s_cz = c0.z;
  }
  __syncthreads();

  for (int k = 0; k < NG - 1; ++k) {
    const float cx = s_cx, cy = s_cy, cz = s_cz;
    float bd = -__builtin_inff();
    int bi = 0;
#pragma unroll
    for (int j = 0; j < 16; ++j) {
      float dx = x[j] - cx;
      float dy = y[j] - cy;
      float dz = z[j] - cz;
      float d = dx * dx + dy * dy + dz * dz;  // contract OFF: matches reference rounding
      float m = fminf(mind[j], d);
      mind[j] = m;
      if (m > bd) { bd = m; bi = t + j * 1024; }  // strict > keeps smallest index in-thread
    }
    // pack (dist asc-ordered bits, ~index) -> max reduce == argmax with first-index ties
    unsigned long long key =
        ((unsigned long long)f32_ord(bd) << 32) | (unsigned)(~(unsigned)bi);
#pragma unroll
    for (int off = 32; off > 0; off >>= 1) {
      unsigned long long o = __shfl_xor(key, off, 64);
      if (o > key) key = o;
    }
    if ((t & 63) == 0) s_wkey[t >> 6] = key;
    __syncthreads();
    // every wave redundantly reduces the 16 wave-partials (no extra barrier)
    unsigned long long kk = s_wkey[t & 15];
#pragma unroll
    for (int off = 8; off > 0; off >>= 1) {
      unsigned long long o = __shfl_xor(kk, off, 64);
      if (o > kk) kk = o;
    }
    const int nxt = (int)(~(unsigned)kk);
    // winner's owning thread publishes center coords straight from registers
    if ((nxt & 1023) == t) {
      const int jj = nxt >> 10;
      float ox = 0.f, oy = 0.f, oz = 0.f;
#pragma unroll
      for (int j = 0; j < 16; ++j) {
        if (j == jj) { ox = x[j]; oy = y[j]; oz = z[j]; }
      }
      s_cx = ox; s_cy = oy; s_cz = oz;
    }
    if (t == 0) s_sel[k + 1] = nxt;
    __syncthreads();
  }

  // write centers = pts[sel] (xyz only), exact input bits
  if (t < NG) {
    int si = s_sel[t];
    float4 p = bp[si];
    size_t o = ((size_t)b * NG + t) * 3;
    centers[o + 0] = p.x;
    centers[o + 1] = p.y;
    centers[o + 2] = p.z;
  }
}

// ---------------- Kernel 2: ball query + energy top-k + gather ----------------
// One wave per (batch, group). Ordered compaction of first 160 in-ball indices,
// then 32 rounds of min-key extraction = top_k by (energy desc, index asc).
__global__ __launch_bounds__(64) void group_kernel(const float4* __restrict__ p4,
                                                   const int* __restrict__ lengths,
                                                   const float* __restrict__ centers,
                                                   float4* __restrict__ outg) {
#pragma clang fp contract(off)
  const int gid = blockIdx.x;
  const int b = gid >> 9;
  const int lane = threadIdx.x;
  const int len = lengths[b];
  const float4* bp = p4 + (size_t)b * N_;
  const float cx = centers[(size_t)gid * 3 + 0];
  const float cy = centers[(size_t)gid * 3 + 1];
  const float cz = centers[(size_t)gid * 3 + 2];

  __shared__ int cand[KORIG];
  int M = 0;  // wave-uniform running in-ball count
  for (int cb = 0; cb < N_ && M < KORIG; cb += 256) {
#pragma unroll
    for (int q = 0; q < 4; ++q) {
      const int i = cb + q * 64 + lane;
      float4 p = bp[i];
      float dx = p.x - cx;
      float dy = p.y - cy;
      float dz = p.z - cz;
      float d2 = dx * dx + dy * dy + dz * dz;  // contract OFF
      const bool pred = (i < len) && (d2 < R2);
      unsigned long long mb = __ballot(pred);
      if (pred) {
        int pos = M + (int)__popcll(mb & ((1ull << lane) - 1ull));
        if (pos < KORIG) cand[pos] = i;  // first-160-by-index semantics
      }
      M += (int)__popcll(mb);
    }
  }
  if (M > KORIG) M = KORIG;
  __syncthreads();

  // keys: (energy desc, index asc) -> ascending u64
  const unsigned long long SENT = ~0ull;
  unsigned long long key0 = SENT, key1 = SENT, key2 = SENT;
  {
    int c0 = lane, c1 = lane + 64, c2 = lane + 128;
    if (c0 < M) { int i = cand[c0]; key0 = ((unsigned long long)(~f32_ord(bp[i].w)) << 32) | (unsigned)i; }
    if (c1 < M) { int i = cand[c1]; key1 = ((unsigned long long)(~f32_ord(bp[i].w)) << 32) | (unsigned)i; }
    if (c2 < M) { int i = cand[c2]; key2 = ((unsigned long long)(~f32_ord(bp[i].w)) << 32) | (unsigned)i; }
  }

  int mysel = -1;  // lane j holds the j-th selected index
  for (int j = 0; j < GS; ++j) {
    unsigned long long kmin = key0 < key1 ? key0 : key1;
    if (key2 < kmin) kmin = key2;
#pragma unroll
    for (int off = 32; off > 0; off >>= 1) {
      unsigned long long o = __shfl_xor(kmin, off, 64);
      if (o < kmin) kmin = o;
    }
    if (kmin == SENT) break;  // fewer than 32 candidates; rest stay -1
    if (lane == j) mysel = (int)(unsigned)kmin;
    if (key0 == kmin) key0 = SENT;
    if (key1 == kmin) key1 = SENT;
    if (key2 == kmin) key2 = SENT;
  }

  const int first = __shfl(mysel, 0, 64);  // highest-energy candidate (or -1 if empty)
  if (lane < GS) {
    int idx = (mysel < 0) ? first : mysel;  // reference: -1 -> idx[:, :, :1]
    float4 o;
    if (idx >= 0) {
      float4 p = bp[idx];
      o.x = (p.x - cx) / RADIUS;
      o.y = (p.y - cy) / RADIUS;
      o.z = (p.z - cz) / RADIUS;
      o.w = p.w / RADIUS;
    } else {
      // masked_gather gives 0, then (0 - center)/radius
      o.x = (0.0f - cx) / RADIUS;
      o.y = (0.0f - cy) / RADIUS;
      o.z = (0.0f - cz) / RADIUS;
      o.w = 0.0f;
    }
    outg[(size_t)gid * GS + lane] = o;
  }
}

extern "C" void kernel_launch(void* const* d_in, const int* in_sizes, int n_in,
                              void* d_out, int out_size, void* d_ws, size_t ws_size,
                              hipStream_t stream) {
  const float4* pts = (const float4*)d_in[0];
  const int* lengths = (const int*)d_in[1];
  float* out = (float*)d_out;
  // layout: groups (8,512,32,4) flat, then centers (8,512,3) flat
  float* centers = out + (size_t)B_ * NG * GS * 4;
  float4* groups = (float4*)out;

  fps_kernel<<<B_, 1024, 0, stream>>>(pts, lengths, centers);
  group_kernel<<<B_ * NG, 64, 0, stream>>>(pts, lengths, centers, groups);
}